// Round 13
// baseline (233.752 us; speedup 1.0000x reference)
//
#include <hip/hip_runtime.h>
#include <hip/hip_bf16.h>

// Attention block: QKV GEMM -> 16-head softmax attention -> proj GEMM.
// B=4, T=2048, C=1024, nh=16, hs=64. All GEMMs in bf16 MFMA, fp32 accum.
// Reference "bug": attn out (B,nh,T,hs) flat is reinterpreted as (B*T, C) for the
// projection -> we just feed the flat [bh][t][d] buffer as proj GEMM's A matrix.
//
// GEMM (r13): 256x128 tile, 8 waves, BK=64 in two k-halves; 4 LDS k-half slots
// ([2buf][2kh], 96KB); per-phase {12 ds_read -> stage 3 -> bar -> lgkm0 -> 16 MFMA
// -> bar}; ONE counted vmcnt(3) per tile (never 0 in loop) = T3/T4 schedule.
// Slot liveness desk-checked: stage(τ+1)k1 @τp1 (other buf), stage(τ+2)k0 @τp2
// (slot dead after τp1, barrier-separated).
// attn (r10, unchanged): swapped QK^T, no-max exp2 softmax, T12 repack,
// ones-MFMA row-sum, LDS-staged K/V dbuf, XCD remap.

typedef __attribute__((ext_vector_type(8)))  short bf16x8;   // MFMA A/B frag
typedef __attribute__((ext_vector_type(4)))  float f32x4;    // 16x16 C/D frag
typedef __attribute__((ext_vector_type(16))) float f32x16;   // 32x32 C/D frag
typedef __attribute__((ext_vector_type(2)))  unsigned u32x2;

typedef __attribute__((address_space(3))) unsigned lds_u32_t;
typedef __attribute__((address_space(1))) unsigned glb_u32_t;

__device__ __forceinline__ void async_cp16(const short* g, short* l) {
    __builtin_amdgcn_global_load_lds((glb_u32_t*)g, (lds_u32_t*)l, 16, 0, 0);
}

__device__ __forceinline__ float exp2fast(float x) {
    return __builtin_amdgcn_exp2f(x);    // v_exp_f32: 2^x
}

__device__ __forceinline__ short f2bf(float f) {
    union { float f; unsigned u; } v; v.f = f;
    unsigned r = v.u + 0x7fffu + ((v.u >> 16) & 1u);   // RNE (inputs are finite)
    return (short)(r >> 16);
}

__device__ __forceinline__ unsigned cvt_pk_bf16(float lo, float hi) {
    unsigned r;
    asm("v_cvt_pk_bf16_f32 %0, %1, %2" : "=v"(r) : "v"(lo), "v"(hi));
    return r;   // bits[15:0]=bf16(lo), bits[31:16]=bf16(hi)
}

// ---------------- fused fp32 -> bf16 conversion (one launch for all 3 inputs) ----
__global__ __launch_bounds__(256) void cvt3_kernel(
    const float4* __restrict__ x,  const float4* __restrict__ ww,
    const float4* __restrict__ pw, short4* __restrict__ xb,
    short4* __restrict__ wwb,      short4* __restrict__ pwb) {
    const int b = blockIdx.x;
    const float4* in; short4* out; int i;
    if (b < 8192)       { in = x;  out = xb;  i = b * 256 + threadIdx.x; }
    else if (b < 11264) { in = ww; out = wwb; i = (b - 8192) * 256 + threadIdx.x; }
    else                { in = pw; out = pwb; i = (b - 11264) * 256 + threadIdx.x; }
    float4 v = in[i];
    short4 o;
    o.x = f2bf(v.x); o.y = f2bf(v.y); o.z = f2bf(v.z); o.w = f2bf(v.w);
    out[i] = o;
}

// ---------------- GEMM: C[m][n] = sum_k A[m][k]*W[n][k] + bias[n] ----------------
// 256x128 tile, 512 threads = 8 waves (4M x 2N), wave owns 64x64 out.
// LDS: lA[2 buf][2 khalf][256x32], lB[2][2][128x32] = 96 KB -> 1 block/CU.
// K-loop per tile (BK=64): p1 computes k-half 0, p2 k-half 1.
//   p1: 12 ds_read; stage (t+1) k1;            bar; lgkm0; 16 MFMA; bar
//   p2: 12 ds_read; stage (t+2) k0; vmcnt(3);  bar; lgkm0; 16 MFMA; bar
// vmcnt(3) leaves only (t+2)k0's 3 loads in flight; (t+1) fully landed.
template<int EPI>
__global__ __launch_bounds__(512) void gemm_bf16(
    const short* __restrict__ A, const short* __restrict__ W,
    const float* __restrict__ bias, float* __restrict__ outF,
    short* __restrict__ kout, short* __restrict__ qout, short* __restrict__ vtout,
    int M, int N, int K)
{
    __shared__ short lA[2][2][256 * 32];
    __shared__ short lB[2][2][128 * 32];
    const int tid  = threadIdx.x;
    const int lane = tid & 63;
    const int wave = tid >> 6;          // 0..7
    const int wr = wave >> 1;           // 0..3 (M)
    const int wc = wave & 1;            // 0..1 (N)
    const int l15 = lane & 15, l4 = lane >> 4;
    const int rowBase = blockIdx.y * 256;
    const int colBase = blockIdx.x * 128;

    // staging geometry: A k-half = 1024 16B-chunks (2/thread), B = 512 (1/thread)
    const int ca0 = tid, ca1 = tid + 512;
    const int ra0 = ca0 >> 2, ra1 = ca1 >> 2, rb = tid >> 2;
    const int sa0 = ((ca0 & 3) ^ (ra0 & 3)) * 8;   // pre-swizzled source chunk
    const int sa1 = ((ca1 & 3) ^ (ra1 & 3)) * 8;
    const int sb  = ((tid & 3) ^ (rb  & 3)) * 8;

    auto STAGE_A = [&](int t, int kh) {
        const short* base = A + (size_t)rowBase * K + t * 64 + kh * 32;
        const int buf = t & 1;
        async_cp16(base + (size_t)ra0 * K + sa0, &lA[buf][kh][ca0 * 8]);
        async_cp16(base + (size_t)ra1 * K + sa1, &lA[buf][kh][ca1 * 8]);
    };
    auto STAGE_B = [&](int t, int kh) {
        const short* base = W + (size_t)colBase * K + t * 64 + kh * 32;
        const int buf = t & 1;
        async_cp16(base + (size_t)rb * K + sb, &lB[buf][kh][tid * 8]);
    };

    f32x4 acc[4][4] = {};

    auto READ = [&](int buf, int kh, bf16x8* af, bf16x8* bfr) {
        #pragma unroll
        for (int mt = 0; mt < 4; ++mt) {
            int row = wr * 64 + mt * 16 + l15;
            af[mt] = *(const bf16x8*)(&lA[buf][kh][row * 32 + ((l4 ^ (row & 3)) * 8)]);
        }
        #pragma unroll
        for (int nt = 0; nt < 4; ++nt) {
            int row = wc * 64 + nt * 16 + l15;
            bfr[nt] = *(const bf16x8*)(&lB[buf][kh][row * 32 + ((l4 ^ (row & 3)) * 8)]);
        }
    };
    auto MFMA16 = [&](bf16x8* af, bf16x8* bfr) {
        #pragma unroll
        for (int mt = 0; mt < 4; ++mt)
            #pragma unroll
            for (int nt = 0; nt < 4; ++nt)
                acc[mt][nt] = __builtin_amdgcn_mfma_f32_16x16x32_bf16(
                    af[mt], bfr[nt], acc[mt][nt], 0, 0, 0);
    };

    const int NT = K >> 6;   // 16 for K=1024

    // prologue: tile0 both halves + tile1 k0 -> 9 loads; keep newest 3 in flight
    STAGE_A(0, 0); STAGE_B(0, 0);
    STAGE_A(0, 1); STAGE_B(0, 1);
    STAGE_A(1, 0); STAGE_B(1, 0);
    asm volatile("s_waitcnt vmcnt(3)" ::: "memory");
    __builtin_amdgcn_s_barrier();

    for (int t = 0; t < NT; ++t) {
        const int buf = t & 1;
        bf16x8 af[4], bfr[4];
        // ---- phase 1: k-half 0
        READ(buf, 0, af, bfr);
        if (t + 1 < NT) { STAGE_A(t + 1, 1); STAGE_B(t + 1, 1); }
        __builtin_amdgcn_s_barrier();
        asm volatile("s_waitcnt lgkmcnt(0)" ::: "memory");
        __builtin_amdgcn_sched_barrier(0);
        __builtin_amdgcn_s_setprio(1);
        MFMA16(af, bfr);
        __builtin_amdgcn_s_setprio(0);
        __builtin_amdgcn_s_barrier();
        // ---- phase 2: k-half 1
        READ(buf, 1, af, bfr);
        if (t + 2 < NT) { STAGE_A(t + 2, 0); STAGE_B(t + 2, 0); }
        asm volatile("s_waitcnt vmcnt(3)" ::: "memory");   // (t+1) fully landed
        __builtin_amdgcn_s_barrier();
        asm volatile("s_waitcnt lgkmcnt(0)" ::: "memory");
        __builtin_amdgcn_sched_barrier(0);
        __builtin_amdgcn_s_setprio(1);
        MFMA16(af, bfr);
        __builtin_amdgcn_s_setprio(0);
        __builtin_amdgcn_s_barrier();
    }

    #pragma unroll
    for (int mt = 0; mt < 4; ++mt) {
        #pragma unroll
        for (int nt = 0; nt < 4; ++nt) {
            const int n  = colBase + wc * 64 + nt * 16 + l15;
            const int mb = rowBase + wr * 64 + mt * 16 + l4 * 4;
            const float bv = bias[n];
            #pragma unroll
            for (int r = 0; r < 4; ++r) {
                const int m = mb + r;
                float val = acc[mt][nt][r] + bv;
                if (EPI == 0) {
                    int b = m >> 11, tt = m & 2047;
                    int j = n >> 10, hd = n & 1023;
                    int h = hd >> 6, d = hd & 63;
                    size_t base = ((size_t)(b * 16 + h) * 2048 + tt) * 64 + d;
                    // fold hs^-0.5 * log2(e) into Q so softmax runs in exp2 domain
                    if (j == 0)      kout[base] = f2bf(val);
                    else if (j == 1) qout[base] = f2bf(val * 0.180336879f);
                    else             vtout[((size_t)(b * 16 + h) * 64 + d) * 2048 + tt] = f2bf(val);
                } else {
                    outF[(size_t)m * N + n] = val;
                }
            }
        }
    }
}

// ---------------- flash attention, swapped-QK^T 32x32x16, LDS-staged K/V --------
// (unchanged from round 10 — passing at 100.6 µs, MfmaUtil 36.6%)
__global__ __launch_bounds__(256) void attn_kernel(
    const short* __restrict__ Q, const short* __restrict__ Km,
    const short* __restrict__ Vt, short* __restrict__ O)
{
    __shared__ short kbuf[2][64 * 64];
    __shared__ short vbuf[2][64 * 64];

    const int tid  = threadIdx.x;
    const int lane = tid & 63;
    const int wave = tid >> 6;
    const int l31 = lane & 31;
    const int l1  = lane >> 5;

    // XCD remap: wg%8 picks the XCD -> give all 16 q-blocks of a head one XCD.
    const int b     = blockIdx.x;
    const int xcd   = b & 7;
    const int inner = b >> 3;
    const int bx    = inner & 15;
    const int bh    = xcd * 8 + (inner >> 4);
    const int q0    = bx * 128 + wave * 32;

    const short* Qh = Q  + (size_t)bh * 2048 * 64;
    const short* Kh = Km + (size_t)bh * 2048 * 64;
    const short* Vh = Vt + (size_t)bh * 64 * 2048;

    const int i8 = lane >> 3, i7 = lane & 7;
    const int srcCol = 8 * (i7 ^ i8);          // pre-swizzled source column (elems)
    const int rsw    = (l31 & 7) << 3;         // read-side swizzle (shorts)

    // Staging: waves 0-1 stage K, waves 2-3 stage V; strength-reduced pointers.
    const short* src[4];
    short* dst0[4];
    int step;
    if (wave < 2) {
        #pragma unroll
        for (int c = 0; c < 4; ++c) {
            int j = wave * 4 + c;
            src[c]  = Kh + (size_t)(8 * j + i8) * 64 + srcCol;
            dst0[c] = &kbuf[0][j * 512 + lane * 8];
        }
        step = 64 * 64;
    } else {
        #pragma unroll
        for (int c = 0; c < 4; ++c) {
            int j = (wave - 2) * 4 + c;
            src[c]  = Vh + (size_t)(8 * j + i8) * 2048 + srcCol;
            dst0[c] = &vbuf[0][j * 512 + lane * 8];
        }
        step = 64;
    }
    auto STAGE = [&](int buf) {
        #pragma unroll
        for (int c = 0; c < 4; ++c) {
            async_cp16(src[c], dst0[c] + buf * 4096);
            src[c] += step;
        }
    };

    // Q as B-operand: n = q = l31, k = d = s*16 + l1*8 + j
    bf16x8 qf[4];
    #pragma unroll
    for (int s = 0; s < 4; ++s)
        qf[s] = *(const bf16x8*)(Qh + (size_t)(q0 + l31) * 64 + s * 16 + l1 * 8);

    // ones B-frag for the row-sum MFMA
    union { unsigned u[4]; bf16x8 v; } onesu;
    #pragma unroll
    for (int j = 0; j < 4; ++j) onesu.u[j] = 0x3F803F80u;
    const bf16x8 onesf = onesu.v;

    f32x16 o[2] = {};
    f32x16 ol   = {};     // row-sums, same reg mapping as o

    STAGE(0);
    __syncthreads();

    int cur = 0;
    for (int it = 0; it < 32; ++it) {
        if (it < 31) STAGE(cur ^ 1);   // prefetch next tile (in flight all phase)

        // ---- QK^T swapped: s2[t] = K_tile(t) x Q  -> D[kv][q], q = l31
        f32x16 s2[2] = {};
        __builtin_amdgcn_s_setprio(1);
        #pragma unroll
        for (int t = 0; t < 2; ++t) {
            #pragma unroll
            for (int s = 0; s < 4; ++s) {
                bf16x8 kf = *(const bf16x8*)(
                    &kbuf[cur][(t * 32 + l31) * 64 + ((s * 16 + l1 * 8) ^ rsw)]);
                s2[t] = __builtin_amdgcn_mfma_f32_32x32x16_bf16(kf, qf[s], s2[t], 0, 0, 0);
            }
        }
        __builtin_amdgcn_s_setprio(0);

        // ---- P = exp2(s) (no max subtraction)
        #pragma unroll
        for (int t = 0; t < 2; ++t)
            #pragma unroll
            for (int i = 0; i < 16; ++i)
                s2[t][i] = exp2fast(s2[t][i]);

        // ---- pack P into A-frags: cvt_pk pairs + permlane32_swap (verified r6)
        bf16x8 pa[4];
        #pragma unroll
        for (int t = 0; t < 2; ++t) {
            #pragma unroll
            for (int sl = 0; sl < 2; ++sl) {
                unsigned A0 = cvt_pk_bf16(s2[t][8 * sl + 0], s2[t][8 * sl + 1]);
                unsigned A1 = cvt_pk_bf16(s2[t][8 * sl + 2], s2[t][8 * sl + 3]);
                unsigned B0 = cvt_pk_bf16(s2[t][8 * sl + 4], s2[t][8 * sl + 5]);
                unsigned B1 = cvt_pk_bf16(s2[t][8 * sl + 6], s2[t][8 * sl + 7]);
                u32x2 ra = __builtin_amdgcn_permlane32_swap(A0, B0, false, false);
                u32x2 rb = __builtin_amdgcn_permlane32_swap(A1, B1, false, false);
                union { unsigned u[4]; bf16x8 v; } w;
                w.u[0] = ra.x;
                w.u[1] = rb.x;
                w.u[2] = ra.y;
                w.u[3] = rb.y;
                pa[2 * t + sl] = w.v;
            }
        }

        // ---- PV + row-sum: o[dt] += P x V, ol += P x 1  (V frags from LDS)
        __builtin_amdgcn_s_setprio(1);
        #pragma unroll
        for (int s = 0; s < 4; ++s) {
            #pragma unroll
            for (int dt = 0; dt < 2; ++dt) {
                bf16x8 vf = *(const bf16x8*)(
                    &vbuf[cur][(dt * 32 + l31) * 64 + ((s * 16 + l1 * 8) ^ rsw)]);
                o[dt] = __builtin_amdgcn_mfma_f32_32x32x16_bf16(pa[s], vf, o[dt], 0, 0, 0);
            }
            ol = __builtin_amdgcn_mfma_f32_32x32x16_bf16(pa[s], onesf, ol, 0, 0, 0);
        }
        __builtin_amdgcn_s_setprio(0);

        __syncthreads();   // drains prefetch (vmcnt 0) + read-done before overwrite
        cur ^= 1;
    }

    // ---- epilogue: normalize by lane-local 1/ol[r] (same reg mapping as o)
    #pragma unroll
    for (int g = 0; g < 4; ++g)
        #pragma unroll
        for (int rr = 0; rr < 4; ++rr) {
            float invl = 1.f / ol[g * 4 + rr];
            int qrow = q0 + rr + 8 * g + 4 * l1;
            size_t base = ((size_t)bh * 2048 + qrow) * 64 + l31;
            O[base]      = f2bf(o[0][g * 4 + rr] * invl);
            O[base + 32] = f2bf(o[1][g * 4 + rr] * invl);
        }
}

// ---------------- launcher ----------------
extern "C" void kernel_launch(void* const* d_in, const int* in_sizes, int n_in,
                              void* d_out, int out_size, void* d_ws, size_t ws_size,
                              hipStream_t stream) {
    const float* x  = (const float*)d_in[0];   // (4,2048,1024)
    const float* ww = (const float*)d_in[1];   // (3072,1024)
    const float* wb = (const float*)d_in[2];   // (3072,)
    const float* pwt = (const float*)d_in[3];  // (1024,1024)
    const float* pb  = (const float*)d_in[4];  // (1024,)
    float* out = (float*)d_out;                // (4,2048,1024) fp32

    short* ws  = (short*)d_ws;
    short* xb  = ws;                      // 8192*1024
    short* wwb = xb  + 8192 * 1024;       // 3072*1024
    short* pwb = wwb + 3072 * 1024;       // 1024*1024
    short* qb  = pwb + 1024 * 1024;       // 64*2048*64  [bh][t][d] (pre-scaled)
    short* kb  = qb  + 64 * 2048 * 64;    // 64*2048*64  [bh][t][d]
    short* vtb = kb  + 64 * 2048 * 64;    // 64*64*2048  [bh][d][t]
    short* ob  = vtb + 64 * 2048 * 64;    // 64*2048*64  flat = proj A matrix

    cvt3_kernel<<<12288, 256, 0, stream>>>(
        (const float4*)x, (const float4*)ww, (const float4*)pwt,
        (short4*)xb, (short4*)wwb, (short4*)pwb);

    gemm_bf16<0><<<dim3(24, 32), 512, 0, stream>>>(
        xb, wwb, wb, nullptr, kb, qb, vtb, 8192, 3072, 1024);

    attn_kernel<<<1024, 256, 0, stream>>>(qb, kb, vtb, ob);

    gemm_bf16<1><<<dim3(8, 32), 512, 0, stream>>>(
        ob, pwb, pb, out, nullptr, nullptr, nullptr, 8192, 1024, 1024);
}

// Round 14
// 205.392 us; speedup vs baseline: 1.1381x; 1.1381x over previous
//
#include <hip/hip_runtime.h>
#include <hip/hip_bf16.h>

// Attention block: QKV GEMM -> 16-head softmax attention -> proj GEMM.
// B=4, T=2048, C=1024, nh=16, hs=64. All GEMMs in bf16 MFMA, fp32 accum.
// Reference "bug": attn out (B,nh,T,hs) flat is reinterpreted as (B*T, C) for the
// projection -> we just feed the flat [bh][t][d] buffer as proj GEMM's A matrix.
//
// GEMM (r12 structure + XCD stripe remap): 128x128 tile, BK=64, 2-slot
// double-buffered global_load_lds prefetch, pre-swizzled source + XOR read.
// Bijective block remap gives each XCD a stripe of 8 consecutive by (A panels
// stay L2-resident: 8 x 256KB = 2MB << 4MB per-XCD L2).
// attn (r10, unchanged): swapped QK^T, no-max exp2 softmax, T12 repack,
// ones-MFMA row-sum, LDS-staged K/V dbuf, XCD remap.

typedef __attribute__((ext_vector_type(8)))  short bf16x8;   // MFMA A/B frag
typedef __attribute__((ext_vector_type(4)))  float f32x4;    // 16x16 C/D frag
typedef __attribute__((ext_vector_type(16))) float f32x16;   // 32x32 C/D frag
typedef __attribute__((ext_vector_type(2)))  unsigned u32x2;

typedef __attribute__((address_space(3))) unsigned lds_u32_t;
typedef __attribute__((address_space(1))) unsigned glb_u32_t;

__device__ __forceinline__ void async_cp16(const short* g, short* l) {
    __builtin_amdgcn_global_load_lds((glb_u32_t*)g, (lds_u32_t*)l, 16, 0, 0);
}

__device__ __forceinline__ float exp2fast(float x) {
    return __builtin_amdgcn_exp2f(x);    // v_exp_f32: 2^x
}

__device__ __forceinline__ short f2bf(float f) {
    union { float f; unsigned u; } v; v.f = f;
    unsigned r = v.u + 0x7fffu + ((v.u >> 16) & 1u);   // RNE (inputs are finite)
    return (short)(r >> 16);
}

__device__ __forceinline__ unsigned cvt_pk_bf16(float lo, float hi) {
    unsigned r;
    asm("v_cvt_pk_bf16_f32 %0, %1, %2" : "=v"(r) : "v"(lo), "v"(hi));
    return r;   // bits[15:0]=bf16(lo), bits[31:16]=bf16(hi)
}

// ---------------- fused fp32 -> bf16 conversion (one launch for all 3 inputs) ----
__global__ __launch_bounds__(256) void cvt3_kernel(
    const float4* __restrict__ x,  const float4* __restrict__ ww,
    const float4* __restrict__ pw, short4* __restrict__ xb,
    short4* __restrict__ wwb,      short4* __restrict__ pwb) {
    const int b = blockIdx.x;
    const float4* in; short4* out; int i;
    if (b < 8192)       { in = x;  out = xb;  i = b * 256 + threadIdx.x; }
    else if (b < 11264) { in = ww; out = wwb; i = (b - 8192) * 256 + threadIdx.x; }
    else                { in = pw; out = pwb; i = (b - 11264) * 256 + threadIdx.x; }
    float4 v = in[i];
    short4 o;
    o.x = f2bf(v.x); o.y = f2bf(v.y); o.z = f2bf(v.z); o.w = f2bf(v.w);
    out[i] = o;
}

// ---------------- GEMM: C[m][n] = sum_k A[m][k]*W[n][k] + bias[n] ----------------
// 128x128 tile, BK=64, 256 threads = 4 waves (2x2), wave owns 64x64 out.
// Double-buffered LDS (64KB): STAGE(t+1) issued BEFORE compute(t); single
// __syncthreads per K-step drains the (covered) prefetch.
// Source col pre-swizzled 8*((idx&7)^(row&7)); read XOR (row&7)*8 -> identity.
// Block remap: XCD x owns by-stripe [8x, 8x+8) for all bx (A panels L2-resident).
template<int EPI>
__global__ __launch_bounds__(256) void gemm_bf16(
    const short* __restrict__ A, const short* __restrict__ W,
    const float* __restrict__ bias, float* __restrict__ outF,
    short* __restrict__ kout, short* __restrict__ qout, short* __restrict__ vtout,
    int M, int N, int K)
{
    __shared__ short lA[2][128 * 64];
    __shared__ short lB[2][128 * 64];
    const int tid  = threadIdx.x;
    const int lane = tid & 63;
    const int wave = tid >> 6;
    const int wM = (wave >> 1) * 64;
    const int wN = (wave & 1) * 64;
    const int l15 = lane & 15, l4 = lane >> 4;
    const int rsw = (lane & 7) << 3;            // read-side XOR (shorts)

    // bijective XCD stripe remap (gridDim.y == 64): lin%8 = XCD = by'/8
    const int lin = blockIdx.y * gridDim.x + blockIdx.x;
    const int byp = 8 * (lin & 7) + ((lin >> 3) & 7);
    const int bxp = lin >> 6;
    const int rowBase = byp * 128;
    const int colBase = bxp * 128;

    auto STAGE = [&](int t, int buf) {
        const int k0 = t * 64;
        #pragma unroll
        for (int i = 0; i < 4; ++i) {
            int idx = i * 256 + tid;
            int r   = idx >> 3;                       // tile row 0..127
            int cp  = ((idx & 7) ^ (r & 7)) * 8;      // pre-swizzled source col
            int eo  = idx * 8;                        // linear LDS offset (shorts)
            async_cp16(A + (size_t)(rowBase + r) * K + k0 + cp, &lA[buf][eo]);
            async_cp16(W + (size_t)(colBase + r) * K + k0 + cp, &lB[buf][eo]);
        }
    };

    f32x4 acc[4][4] = {};
    const int NT = K >> 6;

    STAGE(0, 0);
    __syncthreads();

    int cur = 0;
    for (int t = 0; t < NT; ++t) {
        if (t + 1 < NT) STAGE(t + 1, cur ^ 1);   // prefetch: in flight all phase
        #pragma unroll
        for (int kt = 0; kt < 2; ++kt) {
            bf16x8 af[4], bfr[4];
            #pragma unroll
            for (int mt = 0; mt < 4; ++mt)
                af[mt] = *(const bf16x8*)(
                    &lA[cur][(wM + mt * 16 + l15) * 64 + ((kt * 32 + l4 * 8) ^ rsw)]);
            #pragma unroll
            for (int nt = 0; nt < 4; ++nt)
                bfr[nt] = *(const bf16x8*)(
                    &lB[cur][(wN + nt * 16 + l15) * 64 + ((kt * 32 + l4 * 8) ^ rsw)]);
            #pragma unroll
            for (int mt = 0; mt < 4; ++mt)
                #pragma unroll
                for (int nt = 0; nt < 4; ++nt)
                    acc[mt][nt] = __builtin_amdgcn_mfma_f32_16x16x32_bf16(
                        af[mt], bfr[nt], acc[mt][nt], 0, 0, 0);
        }
        __syncthreads();   // drains prefetch vmcnt + read-done before overwrite
        cur ^= 1;
    }

    #pragma unroll
    for (int mt = 0; mt < 4; ++mt) {
        #pragma unroll
        for (int nt = 0; nt < 4; ++nt) {
            const int n  = colBase + wN + nt * 16 + l15;
            const int mb = rowBase + wM + mt * 16 + l4 * 4;
            const float bv = bias[n];
            #pragma unroll
            for (int r = 0; r < 4; ++r) {
                const int m = mb + r;
                float val = acc[mt][nt][r] + bv;
                if (EPI == 0) {
                    int b = m >> 11, t = m & 2047;
                    int j = n >> 10, hd = n & 1023;
                    int h = hd >> 6, d = hd & 63;
                    size_t base = ((size_t)(b * 16 + h) * 2048 + t) * 64 + d;
                    // fold hs^-0.5 * log2(e) into Q so softmax runs in exp2 domain
                    if (j == 0)      kout[base] = f2bf(val);
                    else if (j == 1) qout[base] = f2bf(val * 0.180336879f);
                    else             vtout[((size_t)(b * 16 + h) * 64 + d) * 2048 + t] = f2bf(val);
                } else {
                    outF[(size_t)m * N + n] = val;
                }
            }
        }
    }
}

// ---------------- flash attention, swapped-QK^T 32x32x16, LDS-staged K/V --------
// (unchanged from round 10 — passing at 100.6 µs, MfmaUtil 36.6%)
__global__ __launch_bounds__(256) void attn_kernel(
    const short* __restrict__ Q, const short* __restrict__ Km,
    const short* __restrict__ Vt, short* __restrict__ O)
{
    __shared__ short kbuf[2][64 * 64];
    __shared__ short vbuf[2][64 * 64];

    const int tid  = threadIdx.x;
    const int lane = tid & 63;
    const int wave = tid >> 6;
    const int l31 = lane & 31;
    const int l1  = lane >> 5;

    // XCD remap: wg%8 picks the XCD -> give all 16 q-blocks of a head one XCD.
    const int b     = blockIdx.x;
    const int xcd   = b & 7;
    const int inner = b >> 3;
    const int bx    = inner & 15;
    const int bh    = xcd * 8 + (inner >> 4);
    const int q0    = bx * 128 + wave * 32;

    const short* Qh = Q  + (size_t)bh * 2048 * 64;
    const short* Kh = Km + (size_t)bh * 2048 * 64;
    const short* Vh = Vt + (size_t)bh * 64 * 2048;

    const int i8 = lane >> 3, i7 = lane & 7;
    const int srcCol = 8 * (i7 ^ i8);          // pre-swizzled source column (elems)
    const int rsw    = (l31 & 7) << 3;         // read-side swizzle (shorts)

    // Staging: waves 0-1 stage K, waves 2-3 stage V; strength-reduced pointers.
    const short* src[4];
    short* dst0[4];
    int step;
    if (wave < 2) {
        #pragma unroll
        for (int c = 0; c < 4; ++c) {
            int j = wave * 4 + c;
            src[c]  = Kh + (size_t)(8 * j + i8) * 64 + srcCol;
            dst0[c] = &kbuf[0][j * 512 + lane * 8];
        }
        step = 64 * 64;
    } else {
        #pragma unroll
        for (int c = 0; c < 4; ++c) {
            int j = (wave - 2) * 4 + c;
            src[c]  = Vh + (size_t)(8 * j + i8) * 2048 + srcCol;
            dst0[c] = &vbuf[0][j * 512 + lane * 8];
        }
        step = 64;
    }
    auto STAGE = [&](int buf) {
        #pragma unroll
        for (int c = 0; c < 4; ++c) {
            async_cp16(src[c], dst0[c] + buf * 4096);
            src[c] += step;
        }
    };

    // Q as B-operand: n = q = l31, k = d = s*16 + l1*8 + j
    bf16x8 qf[4];
    #pragma unroll
    for (int s = 0; s < 4; ++s)
        qf[s] = *(const bf16x8*)(Qh + (size_t)(q0 + l31) * 64 + s * 16 + l1 * 8);

    // ones B-frag for the row-sum MFMA
    union { unsigned u[4]; bf16x8 v; } onesu;
    #pragma unroll
    for (int j = 0; j < 4; ++j) onesu.u[j] = 0x3F803F80u;
    const bf16x8 onesf = onesu.v;

    f32x16 o[2] = {};
    f32x16 ol   = {};     // row-sums, same reg mapping as o

    STAGE(0);
    __syncthreads();

    int cur = 0;
    for (int it = 0; it < 32; ++it) {
        if (it < 31) STAGE(cur ^ 1);   // prefetch next tile (in flight all phase)

        // ---- QK^T swapped: s2[t] = K_tile(t) x Q  -> D[kv][q], q = l31
        f32x16 s2[2] = {};
        __builtin_amdgcn_s_setprio(1);
        #pragma unroll
        for (int t = 0; t < 2; ++t) {
            #pragma unroll
            for (int s = 0; s < 4; ++s) {
                bf16x8 kf = *(const bf16x8*)(
                    &kbuf[cur][(t * 32 + l31) * 64 + ((s * 16 + l1 * 8) ^ rsw)]);
                s2[t] = __builtin_amdgcn_mfma_f32_32x32x16_bf16(kf, qf[s], s2[t], 0, 0, 0);
            }
        }
        __builtin_amdgcn_s_setprio(0);

        // ---- P = exp2(s) (no max subtraction)
        #pragma unroll
        for (int t = 0; t < 2; ++t)
            #pragma unroll
            for (int i = 0; i < 16; ++i)
                s2[t][i] = exp2fast(s2[t][i]);

        // ---- pack P into A-frags: cvt_pk pairs + permlane32_swap (verified r6)
        bf16x8 pa[4];
        #pragma unroll
        for (int t = 0; t < 2; ++t) {
            #pragma unroll
            for (int sl = 0; sl < 2; ++sl) {
                unsigned A0 = cvt_pk_bf16(s2[t][8 * sl + 0], s2[t][8 * sl + 1]);
                unsigned A1 = cvt_pk_bf16(s2[t][8 * sl + 2], s2[t][8 * sl + 3]);
                unsigned B0 = cvt_pk_bf16(s2[t][8 * sl + 4], s2[t][8 * sl + 5]);
                unsigned B1 = cvt_pk_bf16(s2[t][8 * sl + 6], s2[t][8 * sl + 7]);
                u32x2 ra = __builtin_amdgcn_permlane32_swap(A0, B0, false, false);
                u32x2 rb = __builtin_amdgcn_permlane32_swap(A1, B1, false, false);
                union { unsigned u[4]; bf16x8 v; } w;
                w.u[0] = ra.x;
                w.u[1] = rb.x;
                w.u[2] = ra.y;
                w.u[3] = rb.y;
                pa[2 * t + sl] = w.v;
            }
        }

        // ---- PV + row-sum: o[dt] += P x V, ol += P x 1  (V frags from LDS)
        __builtin_amdgcn_s_setprio(1);
        #pragma unroll
        for (int s = 0; s < 4; ++s) {
            #pragma unroll
            for (int dt = 0; dt < 2; ++dt) {
                bf16x8 vf = *(const bf16x8*)(
                    &vbuf[cur][(dt * 32 + l31) * 64 + ((s * 16 + l1 * 8) ^ rsw)]);
                o[dt] = __builtin_amdgcn_mfma_f32_32x32x16_bf16(pa[s], vf, o[dt], 0, 0, 0);
            }
            ol = __builtin_amdgcn_mfma_f32_32x32x16_bf16(pa[s], onesf, ol, 0, 0, 0);
        }
        __builtin_amdgcn_s_setprio(0);

        __syncthreads();   // drains prefetch (vmcnt 0) + read-done before overwrite
        cur ^= 1;
    }

    // ---- epilogue: normalize by lane-local 1/ol[r] (same reg mapping as o)
    #pragma unroll
    for (int g = 0; g < 4; ++g)
        #pragma unroll
        for (int rr = 0; rr < 4; ++rr) {
            float invl = 1.f / ol[g * 4 + rr];
            int qrow = q0 + rr + 8 * g + 4 * l1;
            size_t base = ((size_t)bh * 2048 + qrow) * 64 + l31;
            O[base]      = f2bf(o[0][g * 4 + rr] * invl);
            O[base + 32] = f2bf(o[1][g * 4 + rr] * invl);
        }
}

// ---------------- launcher ----------------
extern "C" void kernel_launch(void* const* d_in, const int* in_sizes, int n_in,
                              void* d_out, int out_size, void* d_ws, size_t ws_size,
                              hipStream_t stream) {
    const float* x  = (const float*)d_in[0];   // (4,2048,1024)
    const float* ww = (const float*)d_in[1];   // (3072,1024)
    const float* wb = (const float*)d_in[2];   // (3072,)
    const float* pwt = (const float*)d_in[3];  // (1024,1024)
    const float* pb  = (const float*)d_in[4];  // (1024,)
    float* out = (float*)d_out;                // (4,2048,1024) fp32

    short* ws  = (short*)d_ws;
    short* xb  = ws;                      // 8192*1024
    short* wwb = xb  + 8192 * 1024;       // 3072*1024
    short* pwb = wwb + 3072 * 1024;       // 1024*1024
    short* qb  = pwb + 1024 * 1024;       // 64*2048*64  [bh][t][d] (pre-scaled)
    short* kb  = qb  + 64 * 2048 * 64;    // 64*2048*64  [bh][t][d]
    short* vtb = kb  + 64 * 2048 * 64;    // 64*64*2048  [bh][d][t]
    short* ob  = vtb + 64 * 2048 * 64;    // 64*2048*64  flat = proj A matrix

    cvt3_kernel<<<12288, 256, 0, stream>>>(
        (const float4*)x, (const float4*)ww, (const float4*)pwt,
        (short4*)xb, (short4*)wwb, (short4*)pwb);

    gemm_bf16<0><<<dim3(24, 64), 256, 0, stream>>>(
        xb, wwb, wb, nullptr, kb, qb, vtb, 8192, 3072, 1024);

    attn_kernel<<<1024, 256, 0, stream>>>(qb, kb, vtb, ob);

    gemm_bf16<1><<<dim3(8, 64), 256, 0, stream>>>(
        ob, pwb, pb, out, nullptr, nullptr, nullptr, 8192, 1024, 1024);
}

// Round 15
// 199.290 us; speedup vs baseline: 1.1729x; 1.0306x over previous
//
#include <hip/hip_runtime.h>
#include <hip/hip_bf16.h>

// Attention block: QKV GEMM -> 16-head softmax attention -> proj GEMM.
// B=4, T=2048, C=1024, nh=16, hs=64. All GEMMs in bf16 MFMA, fp32 accum.
// Reference "bug": attn out (B,nh,T,hs) flat is reinterpreted as (B*T, C) for the
// projection -> we just feed the flat [bh][t][d] buffer as proj GEMM's A matrix.
//
// GEMM (r14, unchanged): 128x128 tile, BK=64, 2-slot dbuf global_load_lds
// prefetch, pre-swizzled source + XOR read, bijective XCD stripe remap.
// attn (r15): T15-style QK-ahead pipeline — QK^T(t+1) MFMAs issue BEFORE
// softmax(t) VALU so the matrix pipe runs under the exp2/pack chain. Same
// 1-barrier-per-tile skeleton; s2a/s2b named (static idx); V staged same-tile.

typedef __attribute__((ext_vector_type(8)))  short bf16x8;   // MFMA A/B frag
typedef __attribute__((ext_vector_type(4)))  float f32x4;    // 16x16 C/D frag
typedef __attribute__((ext_vector_type(16))) float f32x16;   // 32x32 C/D frag
typedef __attribute__((ext_vector_type(2)))  unsigned u32x2;

typedef __attribute__((address_space(3))) unsigned lds_u32_t;
typedef __attribute__((address_space(1))) unsigned glb_u32_t;

__device__ __forceinline__ void async_cp16(const short* g, short* l) {
    __builtin_amdgcn_global_load_lds((glb_u32_t*)g, (lds_u32_t*)l, 16, 0, 0);
}

__device__ __forceinline__ float exp2fast(float x) {
    return __builtin_amdgcn_exp2f(x);    // v_exp_f32: 2^x
}

__device__ __forceinline__ short f2bf(float f) {
    union { float f; unsigned u; } v; v.f = f;
    unsigned r = v.u + 0x7fffu + ((v.u >> 16) & 1u);   // RNE (inputs are finite)
    return (short)(r >> 16);
}

__device__ __forceinline__ unsigned cvt_pk_bf16(float lo, float hi) {
    unsigned r;
    asm("v_cvt_pk_bf16_f32 %0, %1, %2" : "=v"(r) : "v"(lo), "v"(hi));
    return r;   // bits[15:0]=bf16(lo), bits[31:16]=bf16(hi)
}

// ---------------- fused fp32 -> bf16 conversion (one launch for all 3 inputs) ----
__global__ __launch_bounds__(256) void cvt3_kernel(
    const float4* __restrict__ x,  const float4* __restrict__ ww,
    const float4* __restrict__ pw, short4* __restrict__ xb,
    short4* __restrict__ wwb,      short4* __restrict__ pwb) {
    const int b = blockIdx.x;
    const float4* in; short4* out; int i;
    if (b < 8192)       { in = x;  out = xb;  i = b * 256 + threadIdx.x; }
    else if (b < 11264) { in = ww; out = wwb; i = (b - 8192) * 256 + threadIdx.x; }
    else                { in = pw; out = pwb; i = (b - 11264) * 256 + threadIdx.x; }
    float4 v = in[i];
    short4 o;
    o.x = f2bf(v.x); o.y = f2bf(v.y); o.z = f2bf(v.z); o.w = f2bf(v.w);
    out[i] = o;
}

// ---------------- GEMM: C[m][n] = sum_k A[m][k]*W[n][k] + bias[n] ----------------
// (r14, unchanged — 2-phase ceiling + XCD stripe remap)
template<int EPI>
__global__ __launch_bounds__(256) void gemm_bf16(
    const short* __restrict__ A, const short* __restrict__ W,
    const float* __restrict__ bias, float* __restrict__ outF,
    short* __restrict__ kout, short* __restrict__ qout, short* __restrict__ vtout,
    int M, int N, int K)
{
    __shared__ short lA[2][128 * 64];
    __shared__ short lB[2][128 * 64];
    const int tid  = threadIdx.x;
    const int lane = tid & 63;
    const int wave = tid >> 6;
    const int wM = (wave >> 1) * 64;
    const int wN = (wave & 1) * 64;
    const int l15 = lane & 15, l4 = lane >> 4;
    const int rsw = (lane & 7) << 3;            // read-side XOR (shorts)

    // bijective XCD stripe remap (gridDim.y == 64): lin%8 = XCD = by'/8
    const int lin = blockIdx.y * gridDim.x + blockIdx.x;
    const int byp = 8 * (lin & 7) + ((lin >> 3) & 7);
    const int bxp = lin >> 6;
    const int rowBase = byp * 128;
    const int colBase = bxp * 128;

    auto STAGE = [&](int t, int buf) {
        const int k0 = t * 64;
        #pragma unroll
        for (int i = 0; i < 4; ++i) {
            int idx = i * 256 + tid;
            int r   = idx >> 3;                       // tile row 0..127
            int cp  = ((idx & 7) ^ (r & 7)) * 8;      // pre-swizzled source col
            int eo  = idx * 8;                        // linear LDS offset (shorts)
            async_cp16(A + (size_t)(rowBase + r) * K + k0 + cp, &lA[buf][eo]);
            async_cp16(W + (size_t)(colBase + r) * K + k0 + cp, &lB[buf][eo]);
        }
    };

    f32x4 acc[4][4] = {};
    const int NT = K >> 6;

    STAGE(0, 0);
    __syncthreads();

    int cur = 0;
    for (int t = 0; t < NT; ++t) {
        if (t + 1 < NT) STAGE(t + 1, cur ^ 1);   // prefetch: in flight all phase
        #pragma unroll
        for (int kt = 0; kt < 2; ++kt) {
            bf16x8 af[4], bfr[4];
            #pragma unroll
            for (int mt = 0; mt < 4; ++mt)
                af[mt] = *(const bf16x8*)(
                    &lA[cur][(wM + mt * 16 + l15) * 64 + ((kt * 32 + l4 * 8) ^ rsw)]);
            #pragma unroll
            for (int nt = 0; nt < 4; ++nt)
                bfr[nt] = *(const bf16x8*)(
                    &lB[cur][(wN + nt * 16 + l15) * 64 + ((kt * 32 + l4 * 8) ^ rsw)]);
            #pragma unroll
            for (int mt = 0; mt < 4; ++mt)
                #pragma unroll
                for (int nt = 0; nt < 4; ++nt)
                    acc[mt][nt] = __builtin_amdgcn_mfma_f32_16x16x32_bf16(
                        af[mt], bfr[nt], acc[mt][nt], 0, 0, 0);
        }
        __syncthreads();   // drains prefetch vmcnt + read-done before overwrite
        cur ^= 1;
    }

    #pragma unroll
    for (int mt = 0; mt < 4; ++mt) {
        #pragma unroll
        for (int nt = 0; nt < 4; ++nt) {
            const int n  = colBase + wN + nt * 16 + l15;
            const int mb = rowBase + wM + mt * 16 + l4 * 4;
            const float bv = bias[n];
            #pragma unroll
            for (int r = 0; r < 4; ++r) {
                const int m = mb + r;
                float val = acc[mt][nt][r] + bv;
                if (EPI == 0) {
                    int b = m >> 11, t = m & 2047;
                    int j = n >> 10, hd = n & 1023;
                    int h = hd >> 6, d = hd & 63;
                    size_t base = ((size_t)(b * 16 + h) * 2048 + t) * 64 + d;
                    // fold hs^-0.5 * log2(e) into Q so softmax runs in exp2 domain
                    if (j == 0)      kout[base] = f2bf(val);
                    else if (j == 1) qout[base] = f2bf(val * 0.180336879f);
                    else             vtout[((size_t)(b * 16 + h) * 64 + d) * 2048 + t] = f2bf(val);
                } else {
                    outF[(size_t)m * N + n] = val;
                }
            }
        }
    }
}

// ---------------- flash attention, swapped-QK^T 32x32x16, QK-ahead pipeline -----
// grid: 1024 blocks (XCD-remapped), 256 threads = 4 waves; wave owns 32 q-rows.
// Per tile t (1 sync/tile): stage K(t+1),V(t); issue QK(t) MFMAs; THEN run
// softmax+PV of tile t-1 (VALU overlaps the in-flight QK MFMAs); sync.
// Hazards: K(t) staged @t-1 (sync-sep); V(t) read @t+1 (sync-sep), overwritten
// @t+2 (sync-sep). s2a/s2b named per odd/even tile (static reg indexing).
__global__ __launch_bounds__(256) void attn_kernel(
    const short* __restrict__ Q, const short* __restrict__ Km,
    const short* __restrict__ Vt, short* __restrict__ O)
{
    __shared__ short kbuf[2][64 * 64];
    __shared__ short vbuf[2][64 * 64];

    const int tid  = threadIdx.x;
    const int lane = tid & 63;
    const int wave = tid >> 6;
    const int l31 = lane & 31;
    const int l1  = lane >> 5;

    // XCD remap: wg%8 picks the XCD -> give all 16 q-blocks of a head one XCD.
    const int b     = blockIdx.x;
    const int xcd   = b & 7;
    const int inner = b >> 3;
    const int bx    = inner & 15;
    const int bh    = xcd * 8 + (inner >> 4);
    const int q0    = bx * 128 + wave * 32;

    const short* Qh = Q  + (size_t)bh * 2048 * 64;
    const short* Kh = Km + (size_t)bh * 2048 * 64;
    const short* Vh = Vt + (size_t)bh * 64 * 2048;

    const int i8 = lane >> 3, i7 = lane & 7;
    const int srcCol = 8 * (i7 ^ i8);          // pre-swizzled source column (elems)
    const int rsw    = (l31 & 7) << 3;         // read-side swizzle (shorts)

    // Staging: waves 0-1 stage K, waves 2-3 stage V; strength-reduced pointers.
    const short* src[4];
    short* dst0[4];
    int step;
    if (wave < 2) {
        #pragma unroll
        for (int c = 0; c < 4; ++c) {
            int j = wave * 4 + c;
            src[c]  = Kh + (size_t)(8 * j + i8) * 64 + srcCol;
            dst0[c] = &kbuf[0][j * 512 + lane * 8];
        }
        step = 64 * 64;
    } else {
        #pragma unroll
        for (int c = 0; c < 4; ++c) {
            int j = (wave - 2) * 4 + c;
            src[c]  = Vh + (size_t)(8 * j + i8) * 2048 + srcCol;
            dst0[c] = &vbuf[0][j * 512 + lane * 8];
        }
        step = 64;
    }
    auto STAGE_K = [&](int buf) {        // advances K src by one tile per call
        if (wave < 2) {
            #pragma unroll
            for (int c = 0; c < 4; ++c) {
                async_cp16(src[c], dst0[c] + buf * 4096);
                src[c] += step;
            }
        }
    };
    auto STAGE_V = [&](int buf) {        // advances V src by one tile per call
        if (wave >= 2) {
            #pragma unroll
            for (int c = 0; c < 4; ++c) {
                async_cp16(src[c], dst0[c] + buf * 4096);
                src[c] += step;
            }
        }
    };

    // Q as B-operand: n = q = l31, k = d = s*16 + l1*8 + j
    bf16x8 qf[4];
    #pragma unroll
    for (int s = 0; s < 4; ++s)
        qf[s] = *(const bf16x8*)(Qh + (size_t)(q0 + l31) * 64 + s * 16 + l1 * 8);

    // ones B-frag for the row-sum MFMA
    union { unsigned u[4]; bf16x8 v; } onesu;
    #pragma unroll
    for (int j = 0; j < 4; ++j) onesu.u[j] = 0x3F803F80u;
    const bf16x8 onesf = onesu.v;

    f32x16 o[2] = {};
    f32x16 ol   = {};     // row-sums, same reg mapping as o
    f32x16 s2a[2], s2b[2];

    // QK^T swapped: out[t] = K_tile(t-half) x Q -> D[kv][q], q = l31
    auto QK = [&](int kb, f32x16* out) {
        f32x16 r0 = {}, r1 = {};
        __builtin_amdgcn_s_setprio(1);
        #pragma unroll
        for (int s = 0; s < 4; ++s) {
            bf16x8 kf0 = *(const bf16x8*)(
                &kbuf[kb][(l31) * 64 + ((s * 16 + l1 * 8) ^ rsw)]);
            r0 = __builtin_amdgcn_mfma_f32_32x32x16_bf16(kf0, qf[s], r0, 0, 0, 0);
            bf16x8 kf1 = *(const bf16x8*)(
                &kbuf[kb][(32 + l31) * 64 + ((s * 16 + l1 * 8) ^ rsw)]);
            r1 = __builtin_amdgcn_mfma_f32_32x32x16_bf16(kf1, qf[s], r1, 0, 0, 0);
        }
        __builtin_amdgcn_s_setprio(0);
        out[0] = r0; out[1] = r1;
    };

    // softmax (no-max exp2) + pack + PV for a finished score set
    auto SMPV = [&](f32x16* s2, int vb) {
        #pragma unroll
        for (int t = 0; t < 2; ++t)
            #pragma unroll
            for (int i = 0; i < 16; ++i)
                s2[t][i] = exp2fast(s2[t][i]);
        bf16x8 pa[4];
        #pragma unroll
        for (int t = 0; t < 2; ++t) {
            #pragma unroll
            for (int sl = 0; sl < 2; ++sl) {
                unsigned A0 = cvt_pk_bf16(s2[t][8 * sl + 0], s2[t][8 * sl + 1]);
                unsigned A1 = cvt_pk_bf16(s2[t][8 * sl + 2], s2[t][8 * sl + 3]);
                unsigned B0 = cvt_pk_bf16(s2[t][8 * sl + 4], s2[t][8 * sl + 5]);
                unsigned B1 = cvt_pk_bf16(s2[t][8 * sl + 6], s2[t][8 * sl + 7]);
                u32x2 ra = __builtin_amdgcn_permlane32_swap(A0, B0, false, false);
                u32x2 rb = __builtin_amdgcn_permlane32_swap(A1, B1, false, false);
                union { unsigned u[4]; bf16x8 v; } w;
                w.u[0] = ra.x;
                w.u[1] = rb.x;
                w.u[2] = ra.y;
                w.u[3] = rb.y;
                pa[2 * t + sl] = w.v;
            }
        }
        __builtin_amdgcn_s_setprio(1);
        #pragma unroll
        for (int s = 0; s < 4; ++s) {
            #pragma unroll
            for (int dt = 0; dt < 2; ++dt) {
                bf16x8 vf = *(const bf16x8*)(
                    &vbuf[vb][(dt * 32 + l31) * 64 + ((s * 16 + l1 * 8) ^ rsw)]);
                o[dt] = __builtin_amdgcn_mfma_f32_32x32x16_bf16(pa[s], vf, o[dt], 0, 0, 0);
            }
            ol = __builtin_amdgcn_mfma_f32_32x32x16_bf16(pa[s], onesf, ol, 0, 0, 0);
        }
        __builtin_amdgcn_s_setprio(0);
    };

    // ---- prologue: K(0) -> kbuf[0]
    STAGE_K(0);
    __syncthreads();
    // ---- tile 0: stage K(1),V(0); QK(0); (no previous tile)
    STAGE_K(1);
    STAGE_V(0);
    QK(0, s2a);
    __syncthreads();
    // ---- tiles 1..30 in odd/even pairs (15 bodies)
    for (int i = 0; i < 15; ++i) {
        // odd tile t=2i+1: stage K(2i+2)->kb0, V(2i+1)->vb1; QK->s2b; SMPV(tile 2i)
        STAGE_K(0);
        STAGE_V(1);
        QK(1, s2b);
        SMPV(s2a, 0);
        __syncthreads();
        // even tile t=2i+2: stage K(2i+3)->kb1, V(2i+2)->vb0; QK->s2a; SMPV(2i+1)
        STAGE_K(1);
        STAGE_V(0);
        QK(0, s2a);
        SMPV(s2b, 1);
        __syncthreads();
    }
    // ---- tile 31 (odd): no K stage; V(31)->vb1; QK(31)->s2b; SMPV(tile 30)
    STAGE_V(1);
    QK(1, s2b);
    SMPV(s2a, 0);
    __syncthreads();
    // ---- drain: tile 31
    SMPV(s2b, 1);

    // ---- epilogue: normalize by lane-local 1/ol[r] (same reg mapping as o)
    #pragma unroll
    for (int g = 0; g < 4; ++g)
        #pragma unroll
        for (int rr = 0; rr < 4; ++rr) {
            float invl = 1.f / ol[g * 4 + rr];
            int qrow = q0 + rr + 8 * g + 4 * l1;
            size_t base = ((size_t)bh * 2048 + qrow) * 64 + l31;
            O[base]      = f2bf(o[0][g * 4 + rr] * invl);
            O[base + 32] = f2bf(o[1][g * 4 + rr] * invl);
        }
}

// ---------------- launcher ----------------
extern "C" void kernel_launch(void* const* d_in, const int* in_sizes, int n_in,
                              void* d_out, int out_size, void* d_ws, size_t ws_size,
                              hipStream_t stream) {
    const float* x  = (const float*)d_in[0];   // (4,2048,1024)
    const float* ww = (const float*)d_in[1];   // (3072,1024)
    const float* wb = (const float*)d_in[2];   // (3072,)
    const float* pwt = (const float*)d_in[3];  // (1024,1024)
    const float* pb  = (const float*)d_in[4];  // (1024,)
    float* out = (float*)d_out;                // (4,2048,1024) fp32

    short* ws  = (short*)d_ws;
    short* xb  = ws;                      // 8192*1024
    short* wwb = xb  + 8192 * 1024;       // 3072*1024
    short* pwb = wwb + 3072 * 1024;       // 1024*1024
    short* qb  = pwb + 1024 * 1024;       // 64*2048*64  [bh][t][d] (pre-scaled)
    short* kb  = qb  + 64 * 2048 * 64;    // 64*2048*64  [bh][t][d]
    short* vtb = kb  + 64 * 2048 * 64;    // 64*64*2048  [bh][d][t]
    short* ob  = vtb + 64 * 2048 * 64;    // 64*2048*64  flat = proj A matrix

    cvt3_kernel<<<12288, 256, 0, stream>>>(
        (const float4*)x, (const float4*)ww, (const float4*)pwt,
        (short4*)xb, (short4*)wwb, (short4*)pwb);

    gemm_bf16<0><<<dim3(24, 64), 256, 0, stream>>>(
        xb, wwb, wb, nullptr, kb, qb, vtb, 8192, 3072, 1024);

    attn_kernel<<<1024, 256, 0, stream>>>(qb, kb, vtb, ob);

    gemm_bf16<1><<<dim3(8, 64), 256, 0, stream>>>(
        ob, pwb, pb, out, nullptr, nullptr, nullptr, 8192, 1024, 1024);
}